// Round 13
// baseline (141.422 us; speedup 1.0000x reference)
//
#include <hip/hip_runtime.h>
#include <stdint.h>

// Problem constants
#define N_TOK 16384
#define FEAT  256
#define EMB   128
#define NQ    13   // 12 sinc-quadrature nodes (t_q=e^{-10.8+0.9q}) + 1 analytic t=0 tail
#define KC    16   // K-chunks in k2a: 1024 tokens each; partial slab = NQ*KC*64KB = 13.3MB

typedef float  f32x4  __attribute__((ext_vector_type(4)));
typedef __bf16 bf16x8 __attribute__((ext_vector_type(8)));
typedef short  s16x8  __attribute__((ext_vector_type(8)));
typedef unsigned int u32x4 __attribute__((ext_vector_type(4)));

__device__ __forceinline__ unsigned short bf16_rne(float f) {
    union { float f; unsigned u; } v; v.f = f;
    unsigned u = v.u;
    return (unsigned short)((u + 0x7FFFu + ((u >> 16) & 1u)) >> 16);
}
__device__ __forceinline__ float bf16_to_f32(unsigned short s) {
    union { unsigned u; float f; } v; v.u = ((unsigned)s) << 16; return v.f;
}
// 1-op truncation pack: dst = (bf16(b)<<16)|bf16(a) via v_perm_b32 byte select.
__device__ __forceinline__ unsigned pack_perm(float a, float b) {
    union { float f; unsigned u; } ua, ub; ua.f = a; ub.f = b;
    return __builtin_amdgcn_perm(ub.u, ua.u, 0x07060302u);  // bytes: a.2,a.3,b.2,b.3
}
__device__ __forceinline__ void async_cp16(const void* g, void* l) {
    __builtin_amdgcn_global_load_lds(
        (const __attribute__((address_space(1))) unsigned int*)g,
        (__attribute__((address_space(3))) unsigned int*)l, 16, 0, 0);
}

// ---------------- k1: h = x@W1 + b1 ; emit h bf16, hT bf16, UT[q][i] (fused).
// R13: k0 eliminated -- W1 (fp32, row-major [feat][col]) is transposed+converted into
// LDS here via 4x4 micro-tiles, landing in the SAME XOR-swizzled layout the MFMA
// read path already uses (element (n,k) at n*512 + ((k>>3)^(n&15))*16 + (k&7)*2).
__global__ __launch_bounds__(256) void k1_proj(
    const float* __restrict__ x, const float* __restrict__ W1,
    const float* __restrict__ b1,
    unsigned short* __restrict__ h, unsigned short* __restrict__ hT,
    float* __restrict__ UT)
{
    __shared__ __align__(16) unsigned char W1s[65536];   // 128 rows(col) x 512 B(feat)
    __shared__ unsigned short ldsT[128 * 68];
    const int lane = threadIdx.x & 63;
    const int wave = threadIdx.x >> 6;
    const int quad = lane >> 4;
    const int l15  = lane & 15;
    const int arow = blockIdx.x * 64 + wave * 16 + l15;

    // x prologue: 16 independent float4 loads (HBM)
    float4 xv[16];
    #pragma unroll
    for (int ks = 0; ks < 8; ++ks) {
        const float* xp = x + (size_t)arow * FEAT + ks * 32 + quad * 8;
        xv[2 * ks]     = *(const float4*)xp;
        xv[2 * ks + 1] = *(const float4*)(xp + 4);
    }
    // W1 transpose-stage: thread t handles 8 micro-tiles of 4(k) x 4(c)
    {
        const int c0 = (threadIdx.x & 31) * 4;
        #pragma unroll
        for (int i = 0; i < 8; ++i) {
            const int k0 = ((threadIdx.x >> 5) + i * 8) * 4;
            float4 row[4];
            #pragma unroll
            for (int j = 0; j < 4; ++j)
                row[j] = *(const float4*)(W1 + (size_t)(k0 + j) * EMB + c0);
            #pragma unroll
            for (int j2 = 0; j2 < 4; ++j2) {
                const int c = c0 + j2;
                ushort4 pk = make_ushort4(
                    bf16_rne((&row[0].x)[j2]), bf16_rne((&row[1].x)[j2]),
                    bf16_rne((&row[2].x)[j2]), bf16_rne((&row[3].x)[j2]));
                const int blk = (k0 >> 3) ^ (c & 15);
                *(ushort4*)(W1s + c * 512 + blk * 16 + (k0 & 7) * 2) = pk;
            }
        }
    }
    bf16x8 afr[8];
    #pragma unroll
    for (int ks = 0; ks < 8; ++ks) {
        const float4 xa = xv[2 * ks], xb = xv[2 * ks + 1];
        s16x8 at;
        at[0] = (short)bf16_rne(xa.x); at[1] = (short)bf16_rne(xa.y);
        at[2] = (short)bf16_rne(xa.z); at[3] = (short)bf16_rne(xa.w);
        at[4] = (short)bf16_rne(xb.x); at[5] = (short)bf16_rne(xb.y);
        at[6] = (short)bf16_rne(xb.z); at[7] = (short)bf16_rne(xb.w);
        afr[ks] = __builtin_bit_cast(bf16x8, at);
    }
    __syncthreads();   // W1s staged (ds_write drain)

    const f32x4 zero4 = {0.f, 0.f, 0.f, 0.f};
    f32x4 acc[8];
    #pragma unroll
    for (int n0 = 0; n0 < 8; ++n0) acc[n0] = zero4;
    #pragma unroll
    for (int ks = 0; ks < 8; ++ks)
        #pragma unroll
        for (int n0 = 0; n0 < 8; ++n0) {
            const int n = n0 * 16 + l15;
            const int b = (ks * 4 + quad) ^ (n & 15);
            const bf16x8 bfr = *(const bf16x8*)(W1s + n * 512 + b * 16);
            acc[n0] = __builtin_amdgcn_mfma_f32_16x16x32_bf16(afr[ks], bfr, acc[n0], 0, 0, 0);
        }

    const int rbase = blockIdx.x * 64 + wave * 16 + quad * 4;
    float dpart[4] = {0.f, 0.f, 0.f, 0.f};
    #pragma unroll
    for (int n0 = 0; n0 < 8; ++n0) {
        const int col = n0 * 16 + l15;
        const float bias = b1[col];
        unsigned short hb[4];
        #pragma unroll
        for (int r = 0; r < 4; ++r) {
            const float hv = acc[n0][r] + bias;
            const unsigned short q = bf16_rne(hv);
            hb[r] = q;
            const float bb = bf16_to_f32(q);
            dpart[r] += bb * bb;
            h[(size_t)(rbase + r) * EMB + col] = q;
        }
        ushort4 pk = make_ushort4(hb[0], hb[1], hb[2], hb[3]);
        *(ushort4*)&ldsT[col * 68 + wave * 16 + quad * 4] = pk;
    }
    const float tql = __expf(0.9f * (float)l15 - 10.8f);   // lane's quadrature node
    #pragma unroll
    for (int r = 0; r < 4; ++r) {
        float v = dpart[r];
        v += __shfl_xor(v, 1);
        v += __shfl_xor(v, 2);
        v += __shfl_xor(v, 4);
        v += __shfl_xor(v, 8);
        if (l15 < 12)       UT[(size_t)l15 * N_TOK + rbase + r] = __expf(-tql * v);
        else if (l15 == 12) UT[(size_t)12  * N_TOK + rbase + r] = 1.0f;
    }
    __syncthreads();
    const int rbase0 = blockIdx.x * 64;
    #pragma unroll
    for (int i = 0; i < 4; ++i) {
        const int slot = i * 256 + threadIdx.x;
        const int c    = slot >> 3;
        const int seg  = slot & 7;
        const ushort4 a0 = *(const ushort4*)&ldsT[c * 68 + seg * 8];
        const ushort4 a1 = *(const ushort4*)&ldsT[c * 68 + seg * 8 + 4];
        ushort4 o[2] = {a0, a1};
        *(uint4*)&hT[(size_t)c * N_TOK + rbase0 + seg * 8] = *(const uint4*)o;
    }
}

// ---------------- k2a: Gram partials G_q = h^T diag(u^q) h, K split 16 x 1024.
// VALU diet: pack via v_perm (5 ops/pair, was 7). Grid 208, fat blocks.
__global__ __launch_bounds__(256, 3) void k2a_gram(
    const unsigned short* __restrict__ hT, const float* __restrict__ UT,
    float* __restrict__ Gp)
{
    __shared__ __align__(16) unsigned char Rb[32768];   // 128 rows x 256 B (128-token window)
    const int lane = threadIdx.x & 63;
    const int wave = threadIdx.x >> 6;
    const int quad = lane >> 4;
    const int l15  = lane & 15;
    const int q  = blockIdx.x >> 4;     // 0..12
    const int kc = blockIdx.x & 15;     // K-chunk (1024 tokens)
    const int E = wave & 1, F = wave >> 1;

    const f32x4 zero4 = {0.f, 0.f, 0.f, 0.f};
    f32x4 acc[4][4];
    #pragma unroll
    for (int mt = 0; mt < 4; ++mt)
        #pragma unroll
        for (int nt = 0; nt < 4; ++nt) acc[mt][nt] = zero4;

    #pragma unroll 1
    for (int sub = 0; sub < 8; ++sub) {
        const int kwin = kc * 1024 + sub * 128;
        __syncthreads();   // prev sub's LDS reads done
        #pragma unroll
        for (int c = 0; c < 8; ++c) {
            const int chunk = wave * 8 + c;
            const int row = chunk * 4 + (lane >> 4);
            const int b = (lane & 15) ^ (row & 15);
            async_cp16(hT + (size_t)row * N_TOK + kwin + b * 8, Rb + chunk * 1024);
        }
        __syncthreads();   // staged data visible

        #pragma unroll
        for (int ks = 0; ks < 4; ++ks) {
            const int kb = kwin + ks * 32 + quad * 8;
            const float4 ua = *(const float4*)(UT + (size_t)q * N_TOK + kb);
            const float4 ub = *(const float4*)(UT + (size_t)q * N_TOK + kb + 4);
            const float uv[8] = {ua.x, ua.y, ua.z, ua.w, ub.x, ub.y, ub.z, ub.w};
            bf16x8 au[4];
            #pragma unroll
            for (int mt = 0; mt < 4; ++mt) {
                const int re = E * 64 + mt * 16 + l15;
                const int b = (ks * 4 + quad) ^ (re & 15);
                const s16x8 raw = *(const s16x8*)(Rb + re * 256 + b * 16);
                u32x4 ww;
                #pragma unroll
                for (int w = 0; w < 4; ++w) {
                    const float fa = bf16_to_f32((unsigned short)raw[2 * w])     * uv[2 * w];
                    const float fb = bf16_to_f32((unsigned short)raw[2 * w + 1]) * uv[2 * w + 1];
                    ww[w] = pack_perm(fa, fb);
                }
                au[mt] = __builtin_bit_cast(bf16x8, ww);
            }
            #pragma unroll
            for (int nt = 0; nt < 4; ++nt) {
                const int rf = F * 64 + nt * 16 + l15;
                const int b = (ks * 4 + quad) ^ (rf & 15);
                const bf16x8 bfr = *(const bf16x8*)(Rb + rf * 256 + b * 16);
                #pragma unroll
                for (int mt = 0; mt < 4; ++mt)
                    acc[mt][nt] = __builtin_amdgcn_mfma_f32_16x16x32_bf16(au[mt], bfr, acc[mt][nt], 0, 0, 0);
            }
        }
    }

    float* gp = Gp + (size_t)(q * KC + kc) * (EMB * EMB);
    #pragma unroll
    for (int mt = 0; mt < 4; ++mt)
        #pragma unroll
        for (int nt = 0; nt < 4; ++nt)
            #pragma unroll
            for (int r = 0; r < 4; ++r)
                gp[(size_t)(E * 64 + mt * 16 + quad * 4 + r) * EMB + F * 64 + nt * 16 + l15] = acc[mt][nt][r];
}

// ---------------- k2b (fused k2r): GWT[q][o][f] = 2w_q * (W2^T (sum_kc Gp))[o][f], bf16.
// A-frag = W2 column o read directly (64 KB, L2-hot) -- no W2T precompute.
__global__ __launch_bounds__(256) void k2b_gwt(
    const float* __restrict__ Gp, const float* __restrict__ W2,
    unsigned short* __restrict__ GWT)
{
    const int q  = blockIdx.x >> 3;     // 0..12
    const int fs = blockIdx.x & 7;      // f-subtile (16 rows)
    const int lane = threadIdx.x & 63;
    const int wave = threadIdx.x >> 6;
    const int quad = lane >> 4;
    const int l15  = lane & 15;
    const float scale = (q == 12) ? 2.0f * __expf(-10.8f)
                                  : 1.8f * __expf(0.9f * (float)q - 10.8f);  // 2*w_q
    const int fg = fs * 16 + l15;

    const f32x4 zero4 = {0.f, 0.f, 0.f, 0.f};
    f32x4 acc[2];
    acc[0] = zero4; acc[1] = zero4;
    #pragma unroll
    for (int ks = 0; ks < 4; ++ks) {
        float bv[8] = {0,0,0,0,0,0,0,0};
        #pragma unroll
        for (int kc = 0; kc < KC; ++kc) {
            const float* p = Gp + (size_t)(q * KC + kc) * (EMB * EMB) + (size_t)fg * EMB + ks * 32 + quad * 8;
            const float4 x1 = *(const float4*)p;
            const float4 x2 = *(const float4*)(p + 4);
            bv[0] += x1.x; bv[1] += x1.y; bv[2] += x1.z; bv[3] += x1.w;
            bv[4] += x2.x; bv[5] += x2.y; bv[6] += x2.z; bv[7] += x2.w;
        }
        s16x8 sb;
        #pragma unroll
        for (int j = 0; j < 8; ++j) sb[j] = (short)bf16_rne(bv[j]);
        const bf16x8 bfr = __builtin_bit_cast(bf16x8, sb);
        #pragma unroll
        for (int mt = 0; mt < 2; ++mt) {
            const int o = wave * 32 + mt * 16 + l15;
            s16x8 aw;
            #pragma unroll
            for (int j = 0; j < 8; ++j)
                aw[j] = (short)bf16_rne(W2[(size_t)(ks * 32 + quad * 8 + j) * EMB + o]);
            const bf16x8 afr = __builtin_bit_cast(bf16x8, aw);
            acc[mt] = __builtin_amdgcn_mfma_f32_16x16x32_bf16(afr, bfr, acc[mt], 0, 0, 0);
        }
    }
    #pragma unroll
    for (int mt = 0; mt < 2; ++mt)
        #pragma unroll
        for (int r = 0; r < 4; ++r)
            GWT[(size_t)q * (EMB * EMB) + (size_t)(wave * 32 + mt * 16 + quad * 4 + r) * EMB + fs * 16 + l15]
                = bf16_rne(acc[mt][r] * scale);
}

// ---------------- k2c: out[i][o] = relu(b2[o] + sum_q (u_i^q h_i) . GWT_q[o][:])
// R13: 32i x 64o per wave (grid 256, acc 32 AGPR) -- halves per-CU LDS b128 reads
// vs R12's 16i x 64o at 2 blocks/CU. Double-buffered GWT staging, 1 barrier/q.
__global__ __launch_bounds__(256, 2) void k2c_apply(
    const unsigned short* __restrict__ h, const unsigned short* __restrict__ GWT,
    const float* __restrict__ UT, const float* __restrict__ b2,
    float* __restrict__ out)
{
    __shared__ __align__(16) unsigned char Gs[2][32768];
    const int lane = threadIdx.x & 63;
    const int wave = threadIdx.x >> 6;
    const int quad = lane >> 4;
    const int l15  = lane & 15;
    const int i0   = blockIdx.x * 64 + (wave & 1) * 32;   // wave's 32 i-rows (2 groups of 16)
    const int F    = wave >> 1;                           // wave's o-half (64 cols)

    bf16x8 araw[2][4];
    #pragma unroll
    for (int g = 0; g < 2; ++g)
        #pragma unroll
        for (int ks = 0; ks < 4; ++ks)
            araw[g][ks] = *(const bf16x8*)(h + (size_t)(i0 + g * 16 + l15) * EMB + ks * 32 + quad * 8);

    const f32x4 zero4 = {0.f, 0.f, 0.f, 0.f};
    f32x4 acc[2][4];
    #pragma unroll
    for (int g = 0; g < 2; ++g)
        #pragma unroll
        for (int nt = 0; nt < 4; ++nt) acc[g][nt] = zero4;

    #pragma unroll
    for (int c = 0; c < 8; ++c) {
        const int chunk = wave * 8 + c;
        const int row = chunk * 4 + (lane >> 4);
        const int b = (lane & 15) ^ (row & 15);
        async_cp16(GWT + (size_t)row * EMB + b * 8, &Gs[0][chunk * 1024]);
    }
    #pragma unroll 1
    for (int q = 0; q < NQ; ++q) {
        __syncthreads();   // stage(q) complete + prev compute's reads done
        if (q + 1 < NQ) {
            const unsigned short* src = GWT + (size_t)(q + 1) * (EMB * EMB);
            unsigned char* dst = Gs[(q + 1) & 1];
            #pragma unroll
            for (int c = 0; c < 8; ++c) {
                const int chunk = wave * 8 + c;
                const int row = chunk * 4 + (lane >> 4);
                const int b = (lane & 15) ^ (row & 15);
                async_cp16(src + (size_t)row * EMB + b * 8, dst + chunk * 1024);
            }
        }
        bf16x8 au[2][4];
        #pragma unroll
        for (int g = 0; g < 2; ++g) {
            const float u = UT[(size_t)q * N_TOK + i0 + g * 16 + l15];
            #pragma unroll
            for (int ks = 0; ks < 4; ++ks) {
                const s16x8 raw = __builtin_bit_cast(s16x8, araw[g][ks]);
                u32x4 ww;
                #pragma unroll
                for (int w = 0; w < 4; ++w) {
                    const float fa = bf16_to_f32((unsigned short)raw[2 * w])     * u;
                    const float fb = bf16_to_f32((unsigned short)raw[2 * w + 1]) * u;
                    ww[w] = pack_perm(fa, fb);
                }
                au[g][ks] = __builtin_bit_cast(bf16x8, ww);
            }
        }
        const unsigned char* gb = Gs[q & 1];
        #pragma unroll
        for (int nt = 0; nt < 4; ++nt) {
            const int o = F * 64 + nt * 16 + l15;
            #pragma unroll
            for (int ks = 0; ks < 4; ++ks) {
                const int b = (ks * 4 + quad) ^ (o & 15);
                const bf16x8 bfr = *(const bf16x8*)(gb + o * 256 + b * 16);
                #pragma unroll
                for (int g = 0; g < 2; ++g)
                    acc[g][nt] = __builtin_amdgcn_mfma_f32_16x16x32_bf16(au[g][ks], bfr, acc[g][nt], 0, 0, 0);
            }
        }
    }

    #pragma unroll
    for (int g = 0; g < 2; ++g)
        #pragma unroll
        for (int nt = 0; nt < 4; ++nt) {
            const int o = F * 64 + nt * 16 + l15;
            const float bias = b2[o];
            #pragma unroll
            for (int r = 0; r < 4; ++r) {
                const float v = acc[g][nt][r] + bias;
                out[(size_t)(i0 + g * 16 + quad * 4 + r) * EMB + o] = v > 0.f ? v : 0.f;
            }
        }
}

extern "C" void kernel_launch(void* const* d_in, const int* in_sizes, int n_in,
                              void* d_out, int out_size, void* d_ws, size_t ws_size,
                              hipStream_t stream) {
    const float* x  = (const float*)d_in[0];
    const float* W1 = (const float*)d_in[1];
    const float* b1 = (const float*)d_in[2];
    const float* W2 = (const float*)d_in[3];
    const float* b2 = (const float*)d_in[4];
    float* out = (float*)d_out;

    char* ws = (char*)d_ws;
    // ws (bytes): h 4MB | hT 4MB | UT 832KB | Gp 13x16x64KB (13.3MB) | GWT 416KB ~= 22.6MB
    unsigned short* h   = (unsigned short*)(ws);
    unsigned short* hT  = (unsigned short*)(ws + 4194304);
    float*          UT  = (float*)        (ws + 8388608);
    float*          Gp  = (float*)        (ws + 9240576);
    unsigned short* GWT = (unsigned short*)(ws + 22872064);

    k1_proj  <<<dim3(256),     dim3(256), 0, stream>>>(x, W1, b1, h, hT, UT);
    k2a_gram <<<dim3(NQ * KC), dim3(256), 0, stream>>>(hT, UT, Gp);
    k2b_gwt  <<<dim3(NQ * 8),  dim3(256), 0, stream>>>(Gp, W2, GWT);
    k2c_apply<<<dim3(256),     dim3(256), 0, stream>>>(h, GWT, UT, b2, out);
}